// Round 1
// baseline (841.415 us; speedup 1.0000x reference)
//
#include <hip/hip_runtime.h>
#include <hip/hip_bf16.h>

typedef __hip_bfloat16 bf16;

#define HD 16
#define TK 128
#define KP 20            // attn LDS pitch: 16 dims + 4 pad, keeps float4 16B-aligned
#define CT8 32           // flat_attn8 tile positions per wave-chunk
#define MINIT (-1e30f)

__device__ __forceinline__ float b2f(bf16 v){ return __bfloat162float(v); }
__device__ __forceinline__ float gelu_f(float x){ return 0.5f*x*(1.0f+erff(x*0.70710678118654752f)); }
__device__ __forceinline__ float rdv(const void* p, size_t i, bool bf){
  return bf ? b2f(((const bf16*)p)[i]) : ((const float*)p)[i];
}

// ---------------- dtype detector (proven) ----------------
__global__ void detect_k(const void* __restrict__ x, float* __restrict__ flag){
  if (threadIdx.x == 0 && blockIdx.x == 0){
    const float* xf = (const float*)x;
    const bf16*  xb = (const bf16*)x;
    double sF = 0.0, sB = 0.0;
    for (int i = 0; i < 512; i++){ float v = fabsf(xf[i]);     if (!(v < 1e30f)) v = 1e30f; sF += v; }
    for (int i = 0; i < 1024; i++){ float v = fabsf(b2f(xb[i])); if (!(v < 1e30f)) v = 1e30f; sB += v; }
    float mF = (float)(sF/512.0), mB = (float)(sB/1024.0);
    float dF = fabsf(logf(fmaxf(mF, 1e-30f)));
    float dB = fabsf(logf(fmaxf(mB, 1e-30f)));
    *flag = (dB <= dF) ? 1.0f : 0.0f;
  }
}

// ---------------- input -> fp32 convert (proven) ----------------
__global__ void cvt_k(const void* __restrict__ in, float* __restrict__ out, int n,
                      const float* __restrict__ flagp){
  bool bf = *flagp > 0.5f;
  int i = blockIdx.x*blockDim.x + threadIdx.x;
  if (i < n) out[i] = rdv(in, i, bf);
}

// ---------------- wave-split LayerNorm (proven R18) ----------------
__global__ __launch_bounds__(256) void ln2dw_k(
    const float* __restrict__ x, const void* __restrict__ g,
    const void* __restrict__ b, float* __restrict__ y,
    int C, int HW, const float* __restrict__ flagp)
{
  __shared__ float redS[4][64];
  __shared__ float redQ[4][64];
  bool bf = *flagp > 0.5f;
  int t = threadIdx.x, pix = t & 63, sub = t >> 6;
  int p  = blockIdx.x*64 + pix;
  int bb = blockIdx.y;
  const float* xb = x + (size_t)bb*C*HW + p;
  float xv[32];
  float s = 0.f, s2 = 0.f;
  #pragma unroll
  for (int i = 0; i < 32; i++){
    float v = xb[(size_t)(sub*32 + i)*HW];
    xv[i] = v; s += v; s2 += v*v;
  }
  redS[sub][pix] = s; redQ[sub][pix] = s2;
  __syncthreads();
  float st = redS[0][pix] + redS[1][pix] + redS[2][pix] + redS[3][pix];
  float qt = redQ[0][pix] + redQ[1][pix] + redQ[2][pix] + redQ[3][pix];
  float mu  = st / (float)C;
  float var = fmaxf(qt / (float)C - mu*mu, 0.f);
  float inv = rsqrtf(var + 1e-5f);
  float* yb = y + (size_t)bb*C*HW + p;
  #pragma unroll
  for (int i = 0; i < 32; i++){
    int c = sub*32 + i;
    yb[(size_t)c*HW] = (xv[i] - mu)*inv*rdv(g, c, bf) + rdv(b, c, bf);
  }
}

// ---------------- K pre-normalization: k <- k/max(||k||,eps), per 16-dim head group ----------------
// Hoists the cosine-attention K-norm out of every attention kernel (it is query-independent;
// the 36 q-blocks of flat_attn8 were each recomputing it). Mathematically identical.
__global__ void normk_k(float* __restrict__ KV, long kbs, int koff, int NK){
  int p = blockIdx.x*blockDim.x + threadIdx.x;
  if (p >= NK) return;
  int h = blockIdx.y, bb = blockIdx.z;
  float* base = KV + (size_t)bb*kbs + (size_t)(koff + h*16)*NK + p;
  float v[16]; float s = 0.f;
  #pragma unroll
  for (int d = 0; d < 16; d++){ v[d] = base[(size_t)d*NK]; s += v[d]*v[d]; }
  float iv = 1.f / fmaxf(sqrtf(s), 1e-12f);
  #pragma unroll
  for (int d = 0; d < 16; d++) base[(size_t)d*NK] = v[d]*iv;
}

// ---------------- generic scalar 1x1 conv (proven; small NP cases) ----------------
__global__ void conv1x1_k(const float* __restrict__ in1, long in1_bs, int C1,
                          const float* __restrict__ in2, long in2_bs, int C2,
                          const void* __restrict__ w, const void* __restrict__ bias,
                          const float* __restrict__ res,
                          void* __restrict__ out, int to_out, int O, int NP, int act,
                          const float* __restrict__ flagp){
  bool bf = *flagp > 0.5f;
  int p = blockIdx.x*blockDim.x + threadIdx.x;
  if (p >= NP) return;
  int o = blockIdx.y, bb = blockIdx.z;
  size_t wrow = (size_t)o*(C1 + C2);
  float acc = bias ? rdv(bias, o, bf) : 0.f;
  const float* i1 = in1 + (size_t)bb*in1_bs + p;
  for (int c = 0; c < C1; c++) acc += rdv(w, wrow + c, bf) * i1[(size_t)c*NP];
  if (in2){
    const float* i2 = in2 + (size_t)bb*in2_bs + p;
    for (int c = 0; c < C2; c++) acc += rdv(w, wrow + C1 + c, bf) * i2[(size_t)c*NP];
  }
  if (act == 1) acc = gelu_f(acc);
  if (res) acc += res[((size_t)bb*O + o)*NP + p];
  size_t oi = ((size_t)bb*O + o)*NP + p;
  if (to_out){
    if (bf) ((bf16*)out)[oi] = __float2bfloat16(acc);
    else    ((float*)out)[oi] = acc;
  } else {
    ((float*)out)[oi] = acc;
  }
}

// ---------------- LDS-tiled conv GEMM (R17/R18; R19: coalesced+swizzled W staging) ----------------
// W stage: lane -> channel (contiguous 256B global reads) and transposed LDS write with
// XOR swizzle (o ^ ((c&15)<<2)). Swizzle permutes 4-float groups only, so the compute-loop
// float4 read stays 16B-aligned; write conflicts drop 64-way -> 8-way.
#define WSW(c,o) ((c)*64 + ((o) ^ (((c) & 15) << 2)))
__global__ __launch_bounds__(256) void convtile_k(
    const float* __restrict__ in1, long in1_bs, int C1,
    const float* __restrict__ in2, long in2_bs, int C2,
    const void* __restrict__ w, const void* __restrict__ bias,
    const float* __restrict__ res, void* __restrict__ out, int to_out,
    int O, int NP, int act, const float* __restrict__ flagp)
{
  __shared__ __align__(16) float Xs[128*64];
  __shared__ __align__(16) float Wt[128*64];
  bool bf = *flagp > 0.5f;
  int tid = threadIdx.x;
  int p0 = blockIdx.x*64, o0 = blockIdx.y*64, bb = blockIdx.z;
  int CW = C1 + C2;
  int to = (tid >> 4)*4;
  int tp = (tid & 15)*4;
  float a[4][4];
  #pragma unroll
  for (int k = 0; k < 4; k++)
    #pragma unroll
    for (int j = 0; j < 4; j++) a[k][j] = 0.f;
  for (int cc = 0; cc < CW; cc += 128){
    for (int idx = tid; idx < 128*64; idx += 256){
      int c = idx >> 6, j = idx & 63;
      int gc = cc + c;
      float v;
      if (gc < C1) v = in1[(size_t)bb*in1_bs + (size_t)gc*NP + p0 + j];
      else         v = in2[(size_t)bb*in2_bs + (size_t)(gc - C1)*NP + p0 + j];
      Xs[idx] = v;
    }
    {
      int c = tid & 127, ob = tid >> 7;     // lanes sweep c -> coalesced W rows
      #pragma unroll
      for (int k2 = 0; k2 < 32; k2++){
        int o = ob + 2*k2;
        float v = rdv(w, (size_t)(o0 + o)*CW + cc + c, bf);
        Wt[WSW(c, o)] = v;
      }
    }
    __syncthreads();
    for (int c = 0; c < 128; c++){
      float4 wv = *(const float4*)&Wt[WSW(c, to)];
      float4 xv = *(const float4*)&Xs[c*64 + tp];
      a[0][0] += wv.x*xv.x; a[0][1] += wv.x*xv.y; a[0][2] += wv.x*xv.z; a[0][3] += wv.x*xv.w;
      a[1][0] += wv.y*xv.x; a[1][1] += wv.y*xv.y; a[1][2] += wv.y*xv.z; a[1][3] += wv.y*xv.w;
      a[2][0] += wv.z*xv.x; a[2][1] += wv.z*xv.y; a[2][2] += wv.z*xv.z; a[2][3] += wv.z*xv.w;
      a[3][0] += wv.w*xv.x; a[3][1] += wv.w*xv.y; a[3][2] += wv.w*xv.z; a[3][3] += wv.w*xv.w;
    }
    __syncthreads();
  }
  #pragma unroll
  for (int k = 0; k < 4; k++){
    int o = o0 + to + k;
    size_t orow = ((size_t)bb*O + o)*NP + p0 + tp;
    float bv = bias ? rdv(bias, o, bf) : 0.f;
    float v0 = a[k][0] + bv, v1 = a[k][1] + bv, v2 = a[k][2] + bv, v3 = a[k][3] + bv;
    if (act == 1){ v0 = gelu_f(v0); v1 = gelu_f(v1); v2 = gelu_f(v2); v3 = gelu_f(v3); }
    if (res){
      float4 r = *(const float4*)&res[orow];
      v0 += r.x; v1 += r.y; v2 += r.z; v3 += r.w;
    }
    if (to_out && bf){
      bf16* ob = (bf16*)out + orow;
      ob[0] = __float2bfloat16(v0); ob[1] = __float2bfloat16(v1);
      ob[2] = __float2bfloat16(v2); ob[3] = __float2bfloat16(v3);
    } else {
      float4 v; v.x = v0; v.y = v1; v.z = v2; v.w = v3;
      *(float4*)((float*)out + orow) = v;
    }
  }
}

// ---------------- flat cosine attention, 8-wave split-K, 64 queries/block ----------------
// R19: K pre-normalized (no per-tile norm phase), register-prefetch double-buffer so the
// 16 global loads of tile t+1 hide under the ~2300-cycle compute of tile t. 2 barriers/tile.
// NQ % 64 == 0, NK % 8 == 0, (NK/8) % 32 == 0. Local attn: NQ=NK=2304.
__global__ __launch_bounds__(512) void flat_attn8_k(
    const float* __restrict__ Q, long qbs, int qoff,
    const float* __restrict__ KV, long kbs, int koff, int voff,
    float* __restrict__ Out, long obs, int NQ, int NK, float scale)
{
  __shared__ __align__(16) float Ks[8*CT8*KP];   // 5120 floats
  __shared__ __align__(16) float Vs[8*CT8*KP];
  int t = threadIdx.x, lane = t & 63, wv = t >> 6;   // 8 waves
  int h = blockIdx.y, bb = blockIdx.z;
  int qi = blockIdx.x*64 + lane;
  float qn[16]; float s = 0.f;
  #pragma unroll
  for (int d = 0; d < 16; d++){
    qn[d] = Q[(size_t)bb*qbs + (size_t)(qoff + h*16 + d)*NQ + qi];
    s += qn[d]*qn[d];
  }
  float inv = scale / fmaxf(sqrtf(s), 1e-12f);
  #pragma unroll
  for (int d = 0; d < 16; d++) qn[d] *= inv;
  float acc[16]; float l = 0.f;
  #pragma unroll
  for (int d = 0; d < 16; d++) acc[d] = 0.f;
  int chunk = NK >> 3;
  // staging coords: thread t owns (pos = t&31, dd = t>>5) in every slab w2 (t<512 -> dd in 0..15)
  int pos = t & 31, dd = t >> 5;
  const float* kbase = KV + (size_t)bb*kbs + (size_t)(koff + h*16 + dd)*NK + pos;
  const float* vbase = KV + (size_t)bb*kbs + (size_t)(voff + h*16 + dd)*NK + pos;
  float kreg[8], vreg[8];
  #pragma unroll
  for (int w2 = 0; w2 < 8; w2++){         // prefetch tile 0
    kreg[w2] = kbase[(size_t)w2*chunk];
    vreg[w2] = vbase[(size_t)w2*chunk];
  }
  for (int t0 = 0; t0 < chunk; t0 += CT8){
    __syncthreads();                       // previous tile fully consumed
    #pragma unroll
    for (int w2 = 0; w2 < 8; w2++){
      Ks[w2*CT8*KP + pos*KP + dd] = kreg[w2];
      Vs[w2*CT8*KP + pos*KP + dd] = vreg[w2];
    }
    __syncthreads();
    if (t0 + CT8 < chunk){                 // issue next-tile loads; latency hides under compute
      #pragma unroll
      for (int w2 = 0; w2 < 8; w2++){
        kreg[w2] = kbase[(size_t)w2*chunk + t0 + CT8];
        vreg[w2] = vbase[(size_t)w2*chunk + t0 + CT8];
      }
    }
    const float* ks = &Ks[wv*CT8*KP];
    const float* vs = &Vs[wv*CT8*KP];
    for (int p2 = 0; p2 < CT8; p2++){
      float4 a  = *(const float4*)&ks[p2*KP];
      float4 b4 = *(const float4*)&ks[p2*KP + 4];
      float4 c4 = *(const float4*)&ks[p2*KP + 8];
      float4 d4 = *(const float4*)&ks[p2*KP + 12];
      float dot = qn[0]*a.x  + qn[1]*a.y  + qn[2]*a.z  + qn[3]*a.w
                + qn[4]*b4.x + qn[5]*b4.y + qn[6]*b4.z + qn[7]*b4.w
                + qn[8]*c4.x + qn[9]*c4.y + qn[10]*c4.z+ qn[11]*c4.w
                + qn[12]*d4.x+ qn[13]*d4.y+ qn[14]*d4.z+ qn[15]*d4.w;
      float pp = __expf(dot);              // K pre-normalized: dot IS the logit
      l += pp;
      float4 va = *(const float4*)&vs[p2*KP];
      float4 vb = *(const float4*)&vs[p2*KP + 4];
      float4 vc = *(const float4*)&vs[p2*KP + 8];
      float4 vd = *(const float4*)&vs[p2*KP + 12];
      acc[0] += pp*va.x; acc[1] += pp*va.y; acc[2] += pp*va.z; acc[3] += pp*va.w;
      acc[4] += pp*vb.x; acc[5] += pp*vb.y; acc[6] += pp*vb.z; acc[7] += pp*vb.w;
      acc[8] += pp*vc.x; acc[9] += pp*vc.y; acc[10]+= pp*vc.z; acc[11]+= pp*vc.w;
      acc[12]+= pp*vd.x; acc[13]+= pp*vd.y; acc[14]+= pp*vd.z; acc[15]+= pp*vd.w;
    }
  }
  __syncthreads();
  // combine 8 wave-partials: waves 0-3 in Ks slab, 4-7 in Vs slab (max idx 4351 < 5120)
  {
    int slot = (wv & 3)*64 + lane;
    float* slab = (wv < 4) ? Ks : Vs;
    #pragma unroll
    for (int d = 0; d < 16; d++) slab[slot*17 + d] = acc[d];
    slab[slot*17 + 16] = l;
  }
  __syncthreads();
  if (wv == 0){
    float lt = 0.f; float at[16];
    #pragma unroll
    for (int d = 0; d < 16; d++) at[d] = 0.f;
    #pragma unroll
    for (int w2 = 0; w2 < 4; w2++){
      const float* p0 = &Ks[(w2*64 + lane)*17];
      const float* p1 = &Vs[(w2*64 + lane)*17];
      lt += p0[16] + p1[16];
      #pragma unroll
      for (int d = 0; d < 16; d++) at[d] += p0[d] + p1[d];
    }
    float li = 1.f / fmaxf(lt, 1e-30f);
    #pragma unroll
    for (int d = 0; d < 16; d++)
      Out[(size_t)bb*obs + (size_t)(h*16 + d)*NQ + qi] = at[d]*li;
  }
}

// ---------------- attn4, no-max (global attn NK=144 and xw attention NK=16) ----------------
// R19: K pre-normalized -> norm phase and one barrier per tile removed.
__global__ __launch_bounds__(256) void attn4_k(
    const float* __restrict__ Q, long qbs, int qoff,
    const float* __restrict__ KV, long kbs, int koff, int voff,
    float* __restrict__ Out, long obs, int NQ, int NK, float scale)
{
  __shared__ __align__(16) float Ks[TK*KP];
  __shared__ __align__(16) float Vs[TK*KP];
  int tid = threadIdx.x;
  int sub = tid & 3;
  int h = blockIdx.y, bb = blockIdx.z;
  int qi = blockIdx.x*64 + (tid >> 2);
  bool qv = qi < NQ;
  float qn[4] = {0,0,0,0}, acc[4] = {0,0,0,0};
  float l = 0.f;
  if (qv){
    float s = 0.f;
    #pragma unroll
    for (int j = 0; j < 4; j++){
      qn[j] = Q[(size_t)bb*qbs + (size_t)(qoff + h*16 + sub*4 + j)*NQ + qi];
      s += qn[j]*qn[j];
    }
    s += __shfl_xor(s, 1); s += __shfl_xor(s, 2);
    float inv = scale / fmaxf(sqrtf(s), 1e-12f);
    #pragma unroll
    for (int j = 0; j < 4; j++) qn[j] *= inv;
  }
  for (int k0 = 0; k0 < NK; k0 += TK){
    int lim = min(TK, NK - k0);
    for (int i = tid; i < 16*TK; i += 256){
      int pos = i & (TK-1), d = i >> 7;
      if (pos < lim){
        Ks[pos*KP + d] = KV[(size_t)bb*kbs + (size_t)(koff + h*16 + d)*NK + k0 + pos];
        Vs[pos*KP + d] = KV[(size_t)bb*kbs + (size_t)(voff + h*16 + d)*NK + k0 + pos];
      }
    }
    __syncthreads();
    for (int pos = 0; pos < lim; pos++){
      float4 k4 = *(const float4*)&Ks[pos*KP + sub*4];
      float dd = qn[0]*k4.x + qn[1]*k4.y + qn[2]*k4.z + qn[3]*k4.w;
      dd += __shfl_xor(dd, 1); dd += __shfl_xor(dd, 2);
      float pp = __expf(dd);
      l += pp;
      float4 v4 = *(const float4*)&Vs[pos*KP + sub*4];
      acc[0] += pp*v4.x;
      acc[1] += pp*v4.y;
      acc[2] += pp*v4.z;
      acc[3] += pp*v4.w;
    }
    __syncthreads();
  }
  if (qv){
    float li = 1.f / fmaxf(l, 1e-30f);
    #pragma unroll
    for (int j = 0; j < 4; j++)
      Out[(size_t)bb*obs + (size_t)(h*16 + sub*4 + j)*NQ + qi] = acc[j]*li;
  }
}

// ---------------- latent-read attention, split-K partials ----------------
// R19: K pre-normalized (norm per pos removed); no-max softmax (|logit|<=0.25, exp bounded);
// all 64 lanes used: 4 K-sub-chunks per block, shfl_xor(16/32) combine.
__global__ void latpart_k(const float* __restrict__ ql, const float* __restrict__ kvx,
                          long kbs, float* __restrict__ part, int NK, int S){
  int s = blockIdx.x, h = blockIdx.y, bb = blockIdx.z;
  int t = threadIdx.x;
  int q = t & 15, sub = (t >> 4) & 3;
  float qn[16]; float ss = 0.f;
  #pragma unroll
  for (int d = 0; d < 16; d++){
    qn[d] = ql[(size_t)bb*2048 + (size_t)(h*16+d)*16 + q];
    ss += qn[d]*qn[d];
  }
  float inv = 0.25f / fmaxf(sqrtf(ss), 1e-12f);
  #pragma unroll
  for (int d = 0; d < 16; d++) qn[d] *= inv;
  float l = 0.f, acc[16];
  #pragma unroll
  for (int d = 0; d < 16; d++) acc[d] = 0.f;
  int chunk = NK / S, c4 = chunk >> 2;
  int k0 = s*chunk + sub*c4, k1 = k0 + c4;
  const float* kb = kvx + (size_t)bb*kbs;
  for (int pos = k0; pos < k1; pos++){
    float dot = 0.f;
    #pragma unroll
    for (int d = 0; d < 16; d++) dot += qn[d]*kb[(size_t)(h*16+d)*NK + pos];
    float pp = __expf(dot);
    l += pp;
    #pragma unroll
    for (int d = 0; d < 16; d++)
      acc[d] += pp*kb[(size_t)(128 + h*16+d)*NK + pos];
  }
  l += __shfl_xor(l, 16); l += __shfl_xor(l, 32);
  #pragma unroll
  for (int d = 0; d < 16; d++){
    acc[d] += __shfl_xor(acc[d], 16);
    acc[d] += __shfl_xor(acc[d], 32);
  }
  if ((t >> 4) == 0){
    size_t idx = (size_t)((((bb*8 + h)*16 + q)*S) + s)*18;
    part[idx] = l;
    #pragma unroll
    for (int d = 0; d < 16; d++) part[idx+1+d] = acc[d];
  }
}

__global__ void latcomb_k(const float* __restrict__ part, float* __restrict__ latr, int S){
  int t = threadIdx.x;
  int q = t & 15, h = (t >> 4) & 7, bb = t >> 7;
  size_t base = (size_t)(((bb*8 + h)*16 + q)*S)*18;
  float L = 0.f, acc[16];
  #pragma unroll
  for (int d = 0; d < 16; d++) acc[d] = 0.f;
  for (int s = 0; s < S; s++){
    const float* ps = part + base + (size_t)s*18;
    L += ps[0];
    #pragma unroll
    for (int d = 0; d < 16; d++) acc[d] += ps[1+d];
  }
  float li = 1.f / fmaxf(L, 1e-30f);
  #pragma unroll
  for (int d = 0; d < 16; d++)
    latr[(size_t)bb*2048 + (size_t)(h*16+d)*16 + q] = acc[d]*li;
}

// ---------------- 4x4 mean pool (proven) ----------------
__global__ void pool4_k(const float* __restrict__ xn, float* __restrict__ xc){
  int i = blockIdx.x*blockDim.x + threadIdx.x;
  if (i >= 2*128*144) return;
  int pc = i % 144; int bc = i / 144;
  int hc = pc / 12, wc = pc % 12;
  const float* s = xn + (size_t)bc*2304 + hc*4*48 + wc*4;
  float acc = 0.f;
  #pragma unroll
  for (int r = 0; r < 4; r++)
    #pragma unroll
    for (int c2 = 0; c2 < 4; c2++) acc += s[r*48 + c2];
  xc[i] = acc * 0.0625f;
}

// ---------------- bilinear upsample 12->48 (proven) ----------------
__global__ void ups_k(const float* __restrict__ g, float* __restrict__ out){
  int i = blockIdx.x*blockDim.x + threadIdx.x;
  if (i >= 2*128*2304) return;
  int p = i % 2304; int bc = i / 2304;
  int h = p / 48, w = p % 48;
  float sh = h*0.25f - 0.375f;
  float sw = w*0.25f - 0.375f;
  float fh0 = floorf(sh), fw0 = floorf(sw);
  float fh = sh - fh0, fw = sw - fw0;
  int h0 = (int)fh0, w0 = (int)fw0;
  int h0c = min(11, max(0, h0)),   h1c = min(11, max(0, h0+1));
  int w0c = min(11, max(0, w0)),   w1c = min(11, max(0, w0+1));
  const float* s = g + (size_t)bc*144;
  float v00 = s[h0c*12 + w0c], v01 = s[h0c*12 + w1c];
  float v10 = s[h1c*12 + w0c], v11 = s[h1c*12 + w1c];
  out[i] = (1.f-fh)*((1.f-fw)*v00 + fw*v01) + fh*((1.f-fw)*v10 + fw*v11);
}

extern "C" void kernel_launch(void* const* d_in, const int* in_sizes, int n_in,
                              void* d_out, int out_size, void* d_ws, size_t ws_size,
                              hipStream_t stream){
  const int B = 2, C = 128, HW = 2304;
  const void* x_in        = d_in[0];
  const void* g1          = d_in[1];
  const void* b1          = d_in[2];
  const void* loc_qkv_w   = d_in[3];
  const void* loc_proj_w  = d_in[4];
  const void* loc_proj_b  = d_in[5];
  const void* glob_qkv_w  = d_in[6];
  const void* glob_proj_w = d_in[7];
  const void* glob_proj_b = d_in[8];
  const void* fuse_w1     = d_in[9];
  const void* fuse_b1     = d_in[10];
  const void* fuse_w2     = d_in[11];
  const void* fuse_b2     = d_in[12];
  const void* glat        = d_in[13];
  const void* blat        = d_in[14];
  const void* latents     = d_in[15];
  const void* qlat_w      = d_in[16];
  const void* kvx_w       = d_in[17];
  const void* qx_w        = d_in[18];
  const void* kvlat_w     = d_in[19];
  const void* lat_proj_w  = d_in[20];
  const void* lat_proj_b  = d_in[21];
  const void* g2          = d_in[22];
  const void* b2          = d_in[23];
  const void* ffn_w1      = d_in[24];
  const void* ffn_b1      = d_in[25];
  const void* ffn_w2      = d_in[26];
  const void* ffn_b2      = d_in[27];

  // ---- workspace layout VERBATIM (R8..R18) ----
  float* ws = (float*)d_ws;
  float* P  = ws + 0;
  float* N  = ws + 589824;
  float* A  = ws + 1179648;
  float* Q  = ws + 1769472;
  float* FLAG = ws + 4128768;

  float* qkv   = Q;                 // 1,769,472
  float* L     = Q + 1769472;       // 589,824
  float* xc    = Q;
  float* qkvc  = Q + 36864;
  float* gatt  = Q + 147456;
  float* gproj = Q + 184320;
  float* kvx   = Q;                 // 1,179,648
  float* latf  = Q + 1179648;
  float* qlat  = Q + 1181696;
  float* latr  = Q + 1185792;
  float* kvlat = Q + 1189888;
  float* part  = Q + 1198080;       // 221,184 (S=48)
  float* ffh   = Q;                 // 2,359,296

  dim3 blk(256);
  dim3 blk512(512);

  detect_k<<<1, 64, 0, stream>>>(x_in, FLAG);
  cvt_k<<<2304, blk, 0, stream>>>(x_in, P, 589824, FLAG);

  // ---- BioAttentionFusion branch ----
  ln2dw_k<<<dim3(36,B), blk, 0, stream>>>(P, g1, b1, N, C, HW, FLAG);
  convtile_k<<<dim3(36,6,B), blk, 0, stream>>>(N,(long)C*HW,C, nullptr,0,0, loc_qkv_w,nullptr,nullptr, qkv,0,384,HW,0, FLAG);
  normk_k<<<dim3(9,8,B), blk, 0, stream>>>(qkv, (long)384*HW, 128, HW);
  flat_attn8_k<<<dim3(36,8,B), blk512, 0, stream>>>(qkv,(long)384*HW,0, qkv,(long)384*HW,128,256, A,(long)C*HW, HW,HW,0.25f);
  convtile_k<<<dim3(36,2,B), blk, 0, stream>>>(A,(long)C*HW,C, nullptr,0,0, loc_proj_w,loc_proj_b,nullptr, L,0,C,HW,0, FLAG);
  pool4_k<<<144, blk, 0, stream>>>(N, xc);
  conv1x1_k<<<dim3(1,384,B), blk, 0, stream>>>(xc,(long)C*144,C, nullptr,0,0, glob_qkv_w,nullptr,nullptr, qkvc,0,384,144,0, FLAG);
  normk_k<<<dim3(1,8,B), blk, 0, stream>>>(qkvc, (long)384*144, 128, 144);
  attn4_k<<<dim3(3,8,B), blk, 0, stream>>>(qkvc,(long)384*144,0, qkvc,(long)384*144,128,256, gatt,(long)C*144, 144,144,0.25f);
  conv1x1_k<<<dim3(1,128,B), blk, 0, stream>>>(gatt,(long)C*144,C, nullptr,0,0, glob_proj_w,glob_proj_b,nullptr, gproj,0,C,144,0, FLAG);
  ups_k<<<2304, blk, 0, stream>>>(gproj, A);                                          // A = upsampled global
  convtile_k<<<dim3(36,2,B), blk, 0, stream>>>(L,(long)C*HW,C, A,(long)C*HW,C, fuse_w1,fuse_b1,nullptr, N,0,C,HW,1, FLAG);  // N = gelu(fuse1)
  convtile_k<<<dim3(36,2,B), blk, 0, stream>>>(N,(long)C*HW,C, nullptr,0,0, fuse_w2,fuse_b2,P, P,0,C,HW,0, FLAG);           // P = x + f

  // ---- LatentMixer branch ----
  ln2dw_k<<<dim3(36,B), blk, 0, stream>>>(P, glat, blat, N, C, HW, FLAG);
  convtile_k<<<dim3(36,4,B), blk, 0, stream>>>(N,(long)C*HW,C, nullptr,0,0, kvx_w,nullptr,nullptr, kvx,0,256,HW,0, FLAG);
  normk_k<<<dim3(9,8,B), blk, 0, stream>>>(kvx, (long)256*HW, 0, HW);
  convtile_k<<<dim3(36,2,B), blk, 0, stream>>>(N,(long)C*HW,C, nullptr,0,0, qx_w,nullptr,nullptr, A,0,C,HW,0, FLAG);        // A = qx
  cvt_k<<<8, blk, 0, stream>>>(latents, latf, 2048, FLAG);
  conv1x1_k<<<dim3(1,128,B), blk, 0, stream>>>(latf,0L,C, nullptr,0,0, qlat_w,nullptr,nullptr, qlat,0,C,16,0, FLAG);
  latpart_k<<<dim3(48,8,B), 64, 0, stream>>>(qlat, kvx, (long)256*HW, part, HW, 48);
  latcomb_k<<<1, blk, 0, stream>>>(part, latr, 48);
  conv1x1_k<<<dim3(1,256,B), blk, 0, stream>>>(latr,(long)C*16,C, nullptr,0,0, kvlat_w,nullptr,nullptr, kvlat,0,256,16,0, FLAG);
  normk_k<<<dim3(1,8,B), blk, 0, stream>>>(kvlat, (long)256*16, 0, 16);
  attn4_k<<<dim3(36,8,B), blk, 0, stream>>>(A,(long)C*HW,0, kvlat,(long)256*16,0,128, N,(long)C*HW, HW,16,0.25f);           // N = xw
  convtile_k<<<dim3(36,2,B), blk, 0, stream>>>(N,(long)C*HW,C, nullptr,0,0, lat_proj_w,lat_proj_b,P, P,0,C,HW,0, FLAG);     // P = x2

  // ---- FFN branch ----
  ln2dw_k<<<dim3(36,B), blk, 0, stream>>>(P, g2, b2, N, C, HW, FLAG);
  convtile_k<<<dim3(36,8,B), blk, 0, stream>>>(N,(long)C*HW,C, nullptr,0,0, ffn_w1,ffn_b1,nullptr, ffh,0,512,HW,1, FLAG);
  convtile_k<<<dim3(36,2,B), blk, 0, stream>>>(ffh,(long)512*HW,512, nullptr,0,0, ffn_w2,ffn_b2,P, d_out,1,C,HW,0, FLAG);
}

// Round 2
// 752.939 us; speedup vs baseline: 1.1175x; 1.1175x over previous
//
#include <hip/hip_runtime.h>
#include <hip/hip_bf16.h>

typedef __hip_bfloat16 bf16;

#define HD 16
#define TK 128
#define KP 20            // attn LDS pitch: 16 dims + 4 pad, keeps float4 16B-aligned
#define CT8 32           // flat_attn8 tile positions per wave-chunk
#define MINIT (-1e30f)

__device__ __forceinline__ float b2f(bf16 v){ return __bfloat162float(v); }
__device__ __forceinline__ float gelu_f(float x){ return 0.5f*x*(1.0f+erff(x*0.70710678118654752f)); }
__device__ __forceinline__ float rdv(const void* p, size_t i, bool bf){
  return bf ? b2f(((const bf16*)p)[i]) : ((const float*)p)[i];
}

// ---------------- dtype detector (proven) ----------------
__global__ void detect_k(const void* __restrict__ x, float* __restrict__ flag){
  if (threadIdx.x == 0 && blockIdx.x == 0){
    const float* xf = (const float*)x;
    const bf16*  xb = (const bf16*)x;
    double sF = 0.0, sB = 0.0;
    for (int i = 0; i < 512; i++){ float v = fabsf(xf[i]);     if (!(v < 1e30f)) v = 1e30f; sF += v; }
    for (int i = 0; i < 1024; i++){ float v = fabsf(b2f(xb[i])); if (!(v < 1e30f)) v = 1e30f; sB += v; }
    float mF = (float)(sF/512.0), mB = (float)(sB/1024.0);
    float dF = fabsf(logf(fmaxf(mF, 1e-30f)));
    float dB = fabsf(logf(fmaxf(mB, 1e-30f)));
    *flag = (dB <= dF) ? 1.0f : 0.0f;
  }
}

// ---------------- input -> fp32 convert (proven) ----------------
__global__ void cvt_k(const void* __restrict__ in, float* __restrict__ out, int n,
                      const float* __restrict__ flagp){
  bool bf = *flagp > 0.5f;
  int i = blockIdx.x*blockDim.x + threadIdx.x;
  if (i < n) out[i] = rdv(in, i, bf);
}

// ---------------- wave-split LayerNorm (proven R18) ----------------
__global__ __launch_bounds__(256) void ln2dw_k(
    const float* __restrict__ x, const void* __restrict__ g,
    const void* __restrict__ b, float* __restrict__ y,
    int C, int HW, const float* __restrict__ flagp)
{
  __shared__ float redS[4][64];
  __shared__ float redQ[4][64];
  bool bf = *flagp > 0.5f;
  int t = threadIdx.x, pix = t & 63, sub = t >> 6;
  int p  = blockIdx.x*64 + pix;
  int bb = blockIdx.y;
  const float* xb = x + (size_t)bb*C*HW + p;
  float xv[32];
  float s = 0.f, s2 = 0.f;
  #pragma unroll
  for (int i = 0; i < 32; i++){
    float v = xb[(size_t)(sub*32 + i)*HW];
    xv[i] = v; s += v; s2 += v*v;
  }
  redS[sub][pix] = s; redQ[sub][pix] = s2;
  __syncthreads();
  float st = redS[0][pix] + redS[1][pix] + redS[2][pix] + redS[3][pix];
  float qt = redQ[0][pix] + redQ[1][pix] + redQ[2][pix] + redQ[3][pix];
  float mu  = st / (float)C;
  float var = fmaxf(qt / (float)C - mu*mu, 0.f);
  float inv = rsqrtf(var + 1e-5f);
  float* yb = y + (size_t)bb*C*HW + p;
  #pragma unroll
  for (int i = 0; i < 32; i++){
    int c = sub*32 + i;
    yb[(size_t)c*HW] = (xv[i] - mu)*inv*rdv(g, c, bf) + rdv(b, c, bf);
  }
}

// ---------------- K pre-normalization: k <- k/max(||k||,eps), per 16-dim head group ----------------
__global__ void normk_k(float* __restrict__ KV, long kbs, int koff, int NK){
  int p = blockIdx.x*blockDim.x + threadIdx.x;
  if (p >= NK) return;
  int h = blockIdx.y, bb = blockIdx.z;
  float* base = KV + (size_t)bb*kbs + (size_t)(koff + h*16)*NK + p;
  float v[16]; float s = 0.f;
  #pragma unroll
  for (int d = 0; d < 16; d++){ v[d] = base[(size_t)d*NK]; s += v[d]*v[d]; }
  float iv = 1.f / fmaxf(sqrtf(s), 1e-12f);
  #pragma unroll
  for (int d = 0; d < 16; d++) base[(size_t)d*NK] = v[d]*iv;
}

// ---------------- generic scalar 1x1 conv (proven; small NP cases) ----------------
__global__ void conv1x1_k(const float* __restrict__ in1, long in1_bs, int C1,
                          const float* __restrict__ in2, long in2_bs, int C2,
                          const void* __restrict__ w, const void* __restrict__ bias,
                          const float* __restrict__ res,
                          void* __restrict__ out, int to_out, int O, int NP, int act,
                          const float* __restrict__ flagp){
  bool bf = *flagp > 0.5f;
  int p = blockIdx.x*blockDim.x + threadIdx.x;
  if (p >= NP) return;
  int o = blockIdx.y, bb = blockIdx.z;
  size_t wrow = (size_t)o*(C1 + C2);
  float acc = bias ? rdv(bias, o, bf) : 0.f;
  const float* i1 = in1 + (size_t)bb*in1_bs + p;
  for (int c = 0; c < C1; c++) acc += rdv(w, wrow + c, bf) * i1[(size_t)c*NP];
  if (in2){
    const float* i2 = in2 + (size_t)bb*in2_bs + p;
    for (int c = 0; c < C2; c++) acc += rdv(w, wrow + C1 + c, bf) * i2[(size_t)c*NP];
  }
  if (act == 1) acc = gelu_f(acc);
  if (res) acc += res[((size_t)bb*O + o)*NP + p];
  size_t oi = ((size_t)bb*O + o)*NP + p;
  if (to_out){
    if (bf) ((bf16*)out)[oi] = __float2bfloat16(acc);
    else    ((float*)out)[oi] = acc;
  } else {
    ((float*)out)[oi] = acc;
  }
}

// ---------------- LDS-tiled conv GEMM (proven R17/R18 form, W staging reverted to R0) ----------------
__global__ __launch_bounds__(256) void convtile_k(
    const float* __restrict__ in1, long in1_bs, int C1,
    const float* __restrict__ in2, long in2_bs, int C2,
    const void* __restrict__ w, const void* __restrict__ bias,
    const float* __restrict__ res, void* __restrict__ out, int to_out,
    int O, int NP, int act, const float* __restrict__ flagp)
{
  __shared__ __align__(16) float Xs[128*64];
  __shared__ __align__(16) float Wt[128*64];
  bool bf = *flagp > 0.5f;
  int tid = threadIdx.x;
  int p0 = blockIdx.x*64, o0 = blockIdx.y*64, bb = blockIdx.z;
  int CW = C1 + C2;
  int to = (tid >> 4)*4;
  int tp = (tid & 15)*4;
  float a[4][4];
  #pragma unroll
  for (int k = 0; k < 4; k++)
    #pragma unroll
    for (int j = 0; j < 4; j++) a[k][j] = 0.f;
  for (int cc = 0; cc < CW; cc += 128){
    for (int idx = tid; idx < 128*64; idx += 256){
      int c = idx >> 6, j = idx & 63;
      int gc = cc + c;
      float v;
      if (gc < C1) v = in1[(size_t)bb*in1_bs + (size_t)gc*NP + p0 + j];
      else         v = in2[(size_t)bb*in2_bs + (size_t)(gc - C1)*NP + p0 + j];
      Xs[idx] = v;
    }
    for (int idx = tid; idx < 128*64; idx += 256){
      int c = idx >> 6, i = idx & 63;
      Wt[idx] = rdv(w, (size_t)(o0 + i)*CW + cc + c, bf);
    }
    __syncthreads();
    for (int c = 0; c < 128; c++){
      float4 wv = *(const float4*)&Wt[c*64 + to];
      float4 xv = *(const float4*)&Xs[c*64 + tp];
      a[0][0] += wv.x*xv.x; a[0][1] += wv.x*xv.y; a[0][2] += wv.x*xv.z; a[0][3] += wv.x*xv.w;
      a[1][0] += wv.y*xv.x; a[1][1] += wv.y*xv.y; a[1][2] += wv.y*xv.z; a[1][3] += wv.y*xv.w;
      a[2][0] += wv.z*xv.x; a[2][1] += wv.z*xv.y; a[2][2] += wv.z*xv.z; a[2][3] += wv.z*xv.w;
      a[3][0] += wv.w*xv.x; a[3][1] += wv.w*xv.y; a[3][2] += wv.w*xv.z; a[3][3] += wv.w*xv.w;
    }
    __syncthreads();
  }
  #pragma unroll
  for (int k = 0; k < 4; k++){
    int o = o0 + to + k;
    size_t orow = ((size_t)bb*O + o)*NP + p0 + tp;
    float bv = bias ? rdv(bias, o, bf) : 0.f;
    float v0 = a[k][0] + bv, v1 = a[k][1] + bv, v2 = a[k][2] + bv, v3 = a[k][3] + bv;
    if (act == 1){ v0 = gelu_f(v0); v1 = gelu_f(v1); v2 = gelu_f(v2); v3 = gelu_f(v3); }
    if (res){
      float4 r = *(const float4*)&res[orow];
      v0 += r.x; v1 += r.y; v2 += r.z; v3 += r.w;
    }
    if (to_out && bf){
      bf16* ob = (bf16*)out + orow;
      ob[0] = __float2bfloat16(v0); ob[1] = __float2bfloat16(v1);
      ob[2] = __float2bfloat16(v2); ob[3] = __float2bfloat16(v3);
    } else {
      float4 v; v.x = v0; v.y = v1; v.z = v2; v.w = v3;
      *(float4*)((float*)out + orow) = v;
    }
  }
}

// ---------------- flat cosine attention, 8-wave split-K, 144 queries/block ----------------
// R20: LDS-delivery-bound fix. The broadcast ds_read_b128 of K/V (128B/lane/pos) is the
// bottleneck (85M pairs * 128B = 10.9GB LDS traffic at Qpl=1 => ~158us floor, matches R0/R1).
// Amortize each broadcast over ~2.25 queries/lane: 144 queries/block (q0,q1 all lanes; q2 on
// lanes 0-15, computed branchlessly everywhere, stored only where valid). Grid.x=16 -> 256
// blocks = exactly 1/CU (no tail). Staging = R0-proven fused loop; K pre-normalized.
// Hard requirement: NQ == 2304, NK % 256 == 0 (local attn only).
__global__ __launch_bounds__(512) void flat_attn8_k(
    const float* __restrict__ Q, long qbs, int qoff,
    const float* __restrict__ KV, long kbs, int koff, int voff,
    float* __restrict__ Out, long obs, int NQ, int NK, float scale)
{
  __shared__ __align__(16) float S[2*8*CT8*KP];   // Ks = S[0..5119], Vs = S[5120..10239]
  const int VOF = 8*CT8*KP;
  int t = threadIdx.x, lane = t & 63, wv = t >> 6;   // 8 waves
  int h = blockIdx.y, bb = blockIdx.z;
  int qb = blockIdx.x*144;
  int qidx[3];
  qidx[0] = qb + lane;
  qidx[1] = qb + 64 + lane;
  qidx[2] = qb + 128 + (lane & 15);   // valid output only for lane<16; computed by all lanes
  float qn[3][16]; float acc[3][16]; float lsum[3];
  #pragma unroll
  for (int qq = 0; qq < 3; qq++){
    float s = 0.f;
    #pragma unroll
    for (int d = 0; d < 16; d++){
      qn[qq][d] = Q[(size_t)bb*qbs + (size_t)(qoff + h*16 + d)*NQ + qidx[qq]];
      s += qn[qq][d]*qn[qq][d];
    }
    float inv = scale / fmaxf(sqrtf(s), 1e-12f);
    #pragma unroll
    for (int d = 0; d < 16; d++){ qn[qq][d] *= inv; acc[qq][d] = 0.f; }
    lsum[qq] = 0.f;
  }
  int chunk = NK >> 3;
  const float* kvb = KV + (size_t)bb*kbs;
  for (int t0 = 0; t0 < chunk; t0 += CT8){
    __syncthreads();                       // previous tile fully consumed
    for (int i = t; i < 8*CT8*16; i += 512){
      int w2 = i >> 9;                     // slab
      int r  = i & 511;
      int pos = r & 31, d = r >> 5;
      size_t g = (size_t)(h*16 + d)*NK + (size_t)w2*chunk + t0 + pos;
      S[w2*CT8*KP + pos*KP + d]       = kvb[(size_t)koff*NK + g];
      S[VOF + w2*CT8*KP + pos*KP + d] = kvb[(size_t)voff*NK + g];
    }
    __syncthreads();
    const float* ks = &S[wv*CT8*KP];
    const float* vs = &S[VOF + wv*CT8*KP];
    for (int p2 = 0; p2 < CT8; p2++){
      float4 a  = *(const float4*)&ks[p2*KP];
      float4 b4 = *(const float4*)&ks[p2*KP + 4];
      float4 c4 = *(const float4*)&ks[p2*KP + 8];
      float4 d4 = *(const float4*)&ks[p2*KP + 12];
      float4 va = *(const float4*)&vs[p2*KP];
      float4 vb = *(const float4*)&vs[p2*KP + 4];
      float4 vc = *(const float4*)&vs[p2*KP + 8];
      float4 vd = *(const float4*)&vs[p2*KP + 12];
      #pragma unroll
      for (int qq = 0; qq < 3; qq++){
        float dot = qn[qq][0]*a.x  + qn[qq][1]*a.y  + qn[qq][2]*a.z  + qn[qq][3]*a.w
                  + qn[qq][4]*b4.x + qn[qq][5]*b4.y + qn[qq][6]*b4.z + qn[qq][7]*b4.w
                  + qn[qq][8]*c4.x + qn[qq][9]*c4.y + qn[qq][10]*c4.z+ qn[qq][11]*c4.w
                  + qn[qq][12]*d4.x+ qn[qq][13]*d4.y+ qn[qq][14]*d4.z+ qn[qq][15]*d4.w;
        float pp = __expf(dot);            // K pre-normalized: dot IS the logit
        lsum[qq] += pp;
        acc[qq][0] += pp*va.x; acc[qq][1] += pp*va.y; acc[qq][2] += pp*va.z; acc[qq][3] += pp*va.w;
        acc[qq][4] += pp*vb.x; acc[qq][5] += pp*vb.y; acc[qq][6] += pp*vb.z; acc[qq][7] += pp*vb.w;
        acc[qq][8] += pp*vc.x; acc[qq][9] += pp*vc.y; acc[qq][10]+= pp*vc.z; acc[qq][11]+= pp*vc.w;
        acc[qq][12]+= pp*vd.x; acc[qq][13]+= pp*vd.y; acc[qq][14]+= pp*vd.z; acc[qq][15]+= pp*vd.w;
      }
    }
  }
  // combine 8 wave-partials per query group: 3 rounds through LDS (512 slots * 17 <= 10240)
  __syncthreads();
  #pragma unroll
  for (int qq = 0; qq < 3; qq++){
    int slot = wv*64 + lane;
    #pragma unroll
    for (int d = 0; d < 16; d++) S[slot*17 + d] = acc[qq][d];
    S[slot*17 + 16] = lsum[qq];
    __syncthreads();
    if (wv == qq && (qq < 2 || lane < 16)){
      float lt = 0.f; float at[16];
      #pragma unroll
      for (int d = 0; d < 16; d++) at[d] = 0.f;
      #pragma unroll
      for (int w2 = 0; w2 < 8; w2++){
        const float* p0 = &S[(w2*64 + lane)*17];
        lt += p0[16];
        #pragma unroll
        for (int d = 0; d < 16; d++) at[d] += p0[d];
      }
      float li = 1.f / fmaxf(lt, 1e-30f);
      int qi = qidx[qq];
      #pragma unroll
      for (int d = 0; d < 16; d++)
        Out[(size_t)bb*obs + (size_t)(h*16 + d)*NQ + qi] = at[d]*li;
    }
    __syncthreads();
  }
}

// ---------------- attn4, no-max (global attn NK=144 and xw attention NK=16) ----------------
__global__ __launch_bounds__(256) void attn4_k(
    const float* __restrict__ Q, long qbs, int qoff,
    const float* __restrict__ KV, long kbs, int koff, int voff,
    float* __restrict__ Out, long obs, int NQ, int NK, float scale)
{
  __shared__ __align__(16) float Ks[TK*KP];
  __shared__ __align__(16) float Vs[TK*KP];
  int tid = threadIdx.x;
  int sub = tid & 3;
  int h = blockIdx.y, bb = blockIdx.z;
  int qi = blockIdx.x*64 + (tid >> 2);
  bool qv = qi < NQ;
  float qn[4] = {0,0,0,0}, acc[4] = {0,0,0,0};
  float l = 0.f;
  if (qv){
    float s = 0.f;
    #pragma unroll
    for (int j = 0; j < 4; j++){
      qn[j] = Q[(size_t)bb*qbs + (size_t)(qoff + h*16 + sub*4 + j)*NQ + qi];
      s += qn[j]*qn[j];
    }
    s += __shfl_xor(s, 1); s += __shfl_xor(s, 2);
    float inv = scale / fmaxf(sqrtf(s), 1e-12f);
    #pragma unroll
    for (int j = 0; j < 4; j++) qn[j] *= inv;
  }
  for (int k0 = 0; k0 < NK; k0 += TK){
    int lim = min(TK, NK - k0);
    for (int i = tid; i < 16*TK; i += 256){
      int pos = i & (TK-1), d = i >> 7;
      if (pos < lim){
        Ks[pos*KP + d] = KV[(size_t)bb*kbs + (size_t)(koff + h*16 + d)*NK + k0 + pos];
        Vs[pos*KP + d] = KV[(size_t)bb*kbs + (size_t)(voff + h*16 + d)*NK + k0 + pos];
      }
    }
    __syncthreads();
    for (int pos = 0; pos < lim; pos++){
      float4 k4 = *(const float4*)&Ks[pos*KP + sub*4];
      float dd = qn[0]*k4.x + qn[1]*k4.y + qn[2]*k4.z + qn[3]*k4.w;
      dd += __shfl_xor(dd, 1); dd += __shfl_xor(dd, 2);
      float pp = __expf(dd);
      l += pp;
      float4 v4 = *(const float4*)&Vs[pos*KP + sub*4];
      acc[0] += pp*v4.x;
      acc[1] += pp*v4.y;
      acc[2] += pp*v4.z;
      acc[3] += pp*v4.w;
    }
    __syncthreads();
  }
  if (qv){
    float li = 1.f / fmaxf(l, 1e-30f);
    #pragma unroll
    for (int j = 0; j < 4; j++)
      Out[(size_t)bb*obs + (size_t)(h*16 + sub*4 + j)*NQ + qi] = acc[j]*li;
  }
}

// ---------------- latent-read attention, split-K partials ----------------
__global__ void latpart_k(const float* __restrict__ ql, const float* __restrict__ kvx,
                          long kbs, float* __restrict__ part, int NK, int S){
  int s = blockIdx.x, h = blockIdx.y, bb = blockIdx.z;
  int t = threadIdx.x;
  int q = t & 15, sub = (t >> 4) & 3;
  float qn[16]; float ss = 0.f;
  #pragma unroll
  for (int d = 0; d < 16; d++){
    qn[d] = ql[(size_t)bb*2048 + (size_t)(h*16+d)*16 + q];
    ss += qn[d]*qn[d];
  }
  float inv = 0.25f / fmaxf(sqrtf(ss), 1e-12f);
  #pragma unroll
  for (int d = 0; d < 16; d++) qn[d] *= inv;
  float l = 0.f, acc[16];
  #pragma unroll
  for (int d = 0; d < 16; d++) acc[d] = 0.f;
  int chunk = NK / S, c4 = chunk >> 2;
  int k0 = s*chunk + sub*c4, k1 = k0 + c4;
  const float* kb = kvx + (size_t)bb*kbs;
  for (int pos = k0; pos < k1; pos++){
    float dot = 0.f;
    #pragma unroll
    for (int d = 0; d < 16; d++) dot += qn[d]*kb[(size_t)(h*16+d)*NK + pos];
    float pp = __expf(dot);
    l += pp;
    #pragma unroll
    for (int d = 0; d < 16; d++)
      acc[d] += pp*kb[(size_t)(128 + h*16+d)*NK + pos];
  }
  l += __shfl_xor(l, 16); l += __shfl_xor(l, 32);
  #pragma unroll
  for (int d = 0; d < 16; d++){
    acc[d] += __shfl_xor(acc[d], 16);
    acc[d] += __shfl_xor(acc[d], 32);
  }
  if ((t >> 4) == 0){
    size_t idx = (size_t)((((bb*8 + h)*16 + q)*S) + s)*18;
    part[idx] = l;
    #pragma unroll
    for (int d = 0; d < 16; d++) part[idx+1+d] = acc[d];
  }
}

__global__ void latcomb_k(const float* __restrict__ part, float* __restrict__ latr, int S){
  int t = threadIdx.x;
  int q = t & 15, h = (t >> 4) & 7, bb = t >> 7;
  size_t base = (size_t)(((bb*8 + h)*16 + q)*S)*18;
  float L = 0.f, acc[16];
  #pragma unroll
  for (int d = 0; d < 16; d++) acc[d] = 0.f;
  for (int s = 0; s < S; s++){
    const float* ps = part + base + (size_t)s*18;
    L += ps[0];
    #pragma unroll
    for (int d = 0; d < 16; d++) acc[d] += ps[1+d];
  }
  float li = 1.f / fmaxf(L, 1e-30f);
  #pragma unroll
  for (int d = 0; d < 16; d++)
    latr[(size_t)bb*2048 + (size_t)(h*16+d)*16 + q] = acc[d]*li;
}

// ---------------- 4x4 mean pool (proven) ----------------
__global__ void pool4_k(const float* __restrict__ xn, float* __restrict__ xc){
  int i = blockIdx.x*blockDim.x + threadIdx.x;
  if (i >= 2*128*144) return;
  int pc = i % 144; int bc = i / 144;
  int hc = pc / 12, wc = pc % 12;
  const float* s = xn + (size_t)bc*2304 + hc*4*48 + wc*4;
  float acc = 0.f;
  #pragma unroll
  for (int r = 0; r < 4; r++)
    #pragma unroll
    for (int c2 = 0; c2 < 4; c2++) acc += s[r*48 + c2];
  xc[i] = acc * 0.0625f;
}

// ---------------- bilinear upsample 12->48 (proven) ----------------
__global__ void ups_k(const float* __restrict__ g, float* __restrict__ out){
  int i = blockIdx.x*blockDim.x + threadIdx.x;
  if (i >= 2*128*2304) return;
  int p = i % 2304; int bc = i / 2304;
  int h = p / 48, w = p % 48;
  float sh = h*0.25f - 0.375f;
  float sw = w*0.25f - 0.375f;
  float fh0 = floorf(sh), fw0 = floorf(sw);
  float fh = sh - fh0, fw = sw - fw0;
  int h0 = (int)fh0, w0 = (int)fw0;
  int h0c = min(11, max(0, h0)),   h1c = min(11, max(0, h0+1));
  int w0c = min(11, max(0, w0)),   w1c = min(11, max(0, w0+1));
  const float* s = g + (size_t)bc*144;
  float v00 = s[h0c*12 + w0c], v01 = s[h0c*12 + w1c];
  float v10 = s[h1c*12 + w0c], v11 = s[h1c*12 + w1c];
  out[i] = (1.f-fh)*((1.f-fw)*v00 + fw*v01) + fh*((1.f-fw)*v10 + fw*v11);
}

extern "C" void kernel_launch(void* const* d_in, const int* in_sizes, int n_in,
                              void* d_out, int out_size, void* d_ws, size_t ws_size,
                              hipStream_t stream){
  const int B = 2, C = 128, HW = 2304;
  const void* x_in        = d_in[0];
  const void* g1          = d_in[1];
  const void* b1          = d_in[2];
  const void* loc_qkv_w   = d_in[3];
  const void* loc_proj_w  = d_in[4];
  const void* loc_proj_b  = d_in[5];
  const void* glob_qkv_w  = d_in[6];
  const void* glob_proj_w = d_in[7];
  const void* glob_proj_b = d_in[8];
  const void* fuse_w1     = d_in[9];
  const void* fuse_b1     = d_in[10];
  const void* fuse_w2     = d_in[11];
  const void* fuse_b2     = d_in[12];
  const void* glat        = d_in[13];
  const void* blat        = d_in[14];
  const void* latents     = d_in[15];
  const void* qlat_w      = d_in[16];
  const void* kvx_w       = d_in[17];
  const void* qx_w        = d_in[18];
  const void* kvlat_w     = d_in[19];
  const void* lat_proj_w  = d_in[20];
  const void* lat_proj_b  = d_in[21];
  const void* g2          = d_in[22];
  const void* b2          = d_in[23];
  const void* ffn_w1      = d_in[24];
  const void* ffn_b1      = d_in[25];
  const void* ffn_w2      = d_in[26];
  const void* ffn_b2      = d_in[27];

  // ---- workspace layout VERBATIM (R8..R18) ----
  float* ws = (float*)d_ws;
  float* P  = ws + 0;
  float* N  = ws + 589824;
  float* A  = ws + 1179648;
  float* Q  = ws + 1769472;
  float* FLAG = ws + 4128768;

  float* qkv   = Q;                 // 1,769,472
  float* L     = Q + 1769472;       // 589,824
  float* xc    = Q;
  float* qkvc  = Q + 36864;
  float* gatt  = Q + 147456;
  float* gproj = Q + 184320;
  float* kvx   = Q;                 // 1,179,648
  float* latf  = Q + 1179648;
  float* qlat  = Q + 1181696;
  float* latr  = Q + 1185792;
  float* kvlat = Q + 1189888;
  float* part  = Q + 1198080;       // 221,184 (S=48)
  float* ffh   = Q;                 // 2,359,296

  dim3 blk(256);
  dim3 blk512(512);

  detect_k<<<1, 64, 0, stream>>>(x_in, FLAG);
  cvt_k<<<2304, blk, 0, stream>>>(x_in, P, 589824, FLAG);

  // ---- BioAttentionFusion branch ----
  ln2dw_k<<<dim3(36,B), blk, 0, stream>>>(P, g1, b1, N, C, HW, FLAG);
  convtile_k<<<dim3(36,6,B), blk, 0, stream>>>(N,(long)C*HW,C, nullptr,0,0, loc_qkv_w,nullptr,nullptr, qkv,0,384,HW,0, FLAG);
  normk_k<<<dim3(9,8,B), blk, 0, stream>>>(qkv, (long)384*HW, 128, HW);
  flat_attn8_k<<<dim3(16,8,B), blk512, 0, stream>>>(qkv,(long)384*HW,0, qkv,(long)384*HW,128,256, A,(long)C*HW, HW,HW,0.25f);
  convtile_k<<<dim3(36,2,B), blk, 0, stream>>>(A,(long)C*HW,C, nullptr,0,0, loc_proj_w,loc_proj_b,nullptr, L,0,C,HW,0, FLAG);
  pool4_k<<<144, blk, 0, stream>>>(N, xc);
  conv1x1_k<<<dim3(1,384,B), blk, 0, stream>>>(xc,(long)C*144,C, nullptr,0,0, glob_qkv_w,nullptr,nullptr, qkvc,0,384,144,0, FLAG);
  normk_k<<<dim3(1,8,B), blk, 0, stream>>>(qkvc, (long)384*144, 128, 144);
  attn4_k<<<dim3(3,8,B), blk, 0, stream>>>(qkvc,(long)384*144,0, qkvc,(long)384*144,128,256, gatt,(long)C*144, 144,144,0.25f);
  conv1x1_k<<<dim3(1,128,B), blk, 0, stream>>>(gatt,(long)C*144,C, nullptr,0,0, glob_proj_w,glob_proj_b,nullptr, gproj,0,C,144,0, FLAG);
  ups_k<<<2304, blk, 0, stream>>>(gproj, A);                                          // A = upsampled global
  convtile_k<<<dim3(36,2,B), blk, 0, stream>>>(L,(long)C*HW,C, A,(long)C*HW,C, fuse_w1,fuse_b1,nullptr, N,0,C,HW,1, FLAG);  // N = gelu(fuse1)
  convtile_k<<<dim3(36,2,B), blk, 0, stream>>>(N,(long)C*HW,C, nullptr,0,0, fuse_w2,fuse_b2,P, P,0,C,HW,0, FLAG);           // P = x + f

  // ---- LatentMixer branch ----
  ln2dw_k<<<dim3(36,B), blk, 0, stream>>>(P, glat, blat, N, C, HW, FLAG);
  convtile_k<<<dim3(36,4,B), blk, 0, stream>>>(N,(long)C*HW,C, nullptr,0,0, kvx_w,nullptr,nullptr, kvx,0,256,HW,0, FLAG);
  normk_k<<<dim3(9,8,B), blk, 0, stream>>>(kvx, (long)256*HW, 0, HW);
  convtile_k<<<dim3(36,2,B), blk, 0, stream>>>(N,(long)C*HW,C, nullptr,0,0, qx_w,nullptr,nullptr, A,0,C,HW,0, FLAG);        // A = qx
  cvt_k<<<8, blk, 0, stream>>>(latents, latf, 2048, FLAG);
  conv1x1_k<<<dim3(1,128,B), blk, 0, stream>>>(latf,0L,C, nullptr,0,0, qlat_w,nullptr,nullptr, qlat,0,C,16,0, FLAG);
  latpart_k<<<dim3(48,8,B), 64, 0, stream>>>(qlat, kvx, (long)256*HW, part, HW, 48);
  latcomb_k<<<1, blk, 0, stream>>>(part, latr, 48);
  conv1x1_k<<<dim3(1,256,B), blk, 0, stream>>>(latr,(long)C*16,C, nullptr,0,0, kvlat_w,nullptr,nullptr, kvlat,0,256,16,0, FLAG);
  normk_k<<<dim3(1,8,B), blk, 0, stream>>>(kvlat, (long)256*16, 0, 16);
  attn4_k<<<dim3(36,8,B), blk, 0, stream>>>(A,(long)C*HW,0, kvlat,(long)256*16,0,128, N,(long)C*HW, HW,16,0.25f);           // N = xw
  convtile_k<<<dim3(36,2,B), blk, 0, stream>>>(N,(long)C*HW,C, nullptr,0,0, lat_proj_w,lat_proj_b,P, P,0,C,HW,0, FLAG);     // P = x2

  // ---- FFN branch ----
  ln2dw_k<<<dim3(36,B), blk, 0, stream>>>(P, g2, b2, N, C, HW, FLAG);
  convtile_k<<<dim3(36,8,B), blk, 0, stream>>>(N,(long)C*HW,C, nullptr,0,0, ffn_w1,ffn_b1,nullptr, ffh,0,512,HW,1, FLAG);
  convtile_k<<<dim3(36,2,B), blk, 0, stream>>>(ffh,(long)512*HW,512, nullptr,0,0, ffn_w2,ffn_b2,P, d_out,1,C,HW,0, FLAG);
}